// Round 7
// baseline (113.639 us; speedup 1.0000x reference)
//
#include <hip/hip_runtime.h>
#include <hip/hip_bf16.h>
#include <math.h>

#define LOG2PI_F 1.8378770664093453f

typedef __attribute__((ext_vector_type(8))) short bf16x8;
typedef __attribute__((ext_vector_type(4))) float f32x4;
typedef __attribute__((ext_vector_type(16))) float f32x16;

static __device__ inline short f2bf(float x) {
  __hip_bfloat16 h = __float2bfloat16(x);
  return *reinterpret_cast<short*>(&h);
}
// HW packed f32->bf16 (RNE). Session A/B (r1 vs r2) showed >= sw pack here.
static __device__ inline unsigned cvtpk(float lo, float hi) {
  unsigned r;
  asm("v_cvt_pk_bf16_f32 %0, %1, %2" : "=v"(r) : "v"(lo), "v"(hi));
  return r;
}
static __device__ inline f32x4 mfma16(bf16x8 a, bf16x8 b, f32x4 c) {
  return __builtin_amdgcn_mfma_f32_16x16x32_bf16(a, b, c, 0, 0, 0);
}
static __device__ inline f32x16 mfma32(bf16x8 a, bf16x8 b, f32x16 c) {
  return __builtin_amdgcn_mfma_f32_32x32x16_bf16(a, b, c, 0, 0, 0);
}

// ---------------- K012: fused prep (WTbf + Gt/const_c + XeP) ----------------
__global__ __launch_bounds__(256) void mmm_prep_fused(
    const float* __restrict__ tl, const float* __restrict__ means,
    const float* __restrict__ log_vars, const float* __restrict__ weight_logits,
    const float* __restrict__ X,
    short* __restrict__ WTbf, short* __restrict__ Gt,
    float* __restrict__ const_c, short* __restrict__ XeP) {
  __shared__ float red[4];
  int bid = blockIdx.x;
  int tid = threadIdx.x;

  if (bid < 64) {               // ---- K0 ----
    if (tid < 64) {
      int r = bid, lane = tid;
      float v = tl[r * 64 + lane];
      float mx = v;
      #pragma unroll
      for (int off = 1; off < 64; off <<= 1) mx = fmaxf(mx, __shfl_xor(mx, off));
      float e = expf(v - mx);
      float s = e;
      #pragma unroll
      for (int off = 1; off < 64; off <<= 1) s += __shfl_xor(s, off);
      WTbf[lane * 64 + r] = f2bf(e / s);
    }
    return;
  }

  if (bid < 320) {              // ---- K1 (2 sm per block) ----
    int h = tid >> 7, d = tid & 127;
    int sm = (bid - 64) * 2 + h;
    int s = sm >> 3, m = sm & 7;
    float lv = log_vars[sm * 128 + d];
    float iv = expf(-lv);
    float mu = means[sm * 128 + d];
    float miv = mu * iv;
    Gt[sm * 256 + d] = f2bf(miv);
    Gt[sm * 256 + 128 + d] = f2bf(-0.5f * iv);
    float v = mu * miv + lv;
    #pragma unroll
    for (int off = 1; off < 64; off <<= 1) v += __shfl_xor(v, off);
    if ((tid & 63) == 0) red[tid >> 6] = v;
    __syncthreads();
    if (d == 0) {
      float tot = red[2 * h] + red[2 * h + 1];
      float wl[8];
      float mx = -3.4e38f;
      #pragma unroll
      for (int j = 0; j < 8; ++j) { wl[j] = weight_logits[s * 8 + j]; mx = fmaxf(mx, wl[j]); }
      float sum = 0.f;
      #pragma unroll
      for (int j = 0; j < 8; ++j) sum += expf(wl[j] - mx);
      float lmw = wl[m] - mx - logf(sum);
      const_c[sm] = -0.5f * (tot + 128.0f * LOG2PI_F) + lmw;
    }
    return;
  }

  // ---- K2 ----
  int kbid = bid - 320;
  int q = kbid >> 7;
  int bt = ((kbid & 127) << 8) + tid;
  const float4* src = (const float4*)(X + (size_t)bt * 128 + q * 32);
  float xv[32];
  #pragma unroll
  for (int i = 0; i < 8; ++i) {
    float4 v = src[i];
    xv[4 * i] = v.x; xv[4 * i + 1] = v.y; xv[4 * i + 2] = v.z; xv[4 * i + 3] = v.w;
  }
  size_t base1 = ((size_t)q * 32768 + bt) * 32;
  size_t base2 = ((size_t)(q + 4) * 32768 + bt) * 32;
  int bx = bt & 3;
  #pragma unroll
  for (int g = 0; g < 4; ++g) {
    unsigned w1[4], w2[4];
    #pragma unroll
    for (int j = 0; j < 4; ++j) {
      float a = xv[g * 8 + 2 * j], c = xv[g * 8 + 2 * j + 1];
      w1[j] = cvtpk(a, c);
      w2[j] = cvtpk(a * a, c * c);
    }
    int gs = (g ^ bx) * 8;
    *(uint4*)&XeP[base1 + gs] = *(uint4*)w1;
    *(uint4*)&XeP[base2 + gs] = *(uint4*)w2;
  }
}

// ---------------- K3: MFMA emission GEMM, C[sm=512][bt=64-tile] ------------
__global__ __launch_bounds__(512) void mmm_emis_kernel(
    const short* __restrict__ Gt, const short* __restrict__ XeP,
    const float* __restrict__ const_c,
    float* __restrict__ ehat, float* __restrict__ cmax) {
  __shared__ __align__(16) short Bt[16384];  // 32 KB
  __shared__ __align__(16) float ccs[512];
  __shared__ float wavemax[8][64];
  __shared__ float colmax[64];
  int tid = threadIdx.x;
  int w = tid >> 6, lane = tid & 63, lr = lane & 15, lg = lane >> 4;

  ccs[tid] = const_c[tid];

  bf16x8 gf[4][8];
  #pragma unroll
  for (int rt = 0; rt < 4; ++rt) {
    int row = w * 64 + rt * 16 + lr;
    #pragma unroll
    for (int kc = 0; kc < 8; ++kc)
      gf[rt][kc] = *(const bf16x8*)&Gt[row * 256 + kc * 32 + lg * 8];
  }

  uint4 sreg[4];
  {
    size_t bt0 = (size_t)blockIdx.x * 64;
    #pragma unroll
    for (int r = 0; r < 4; ++r) {
      int ofs = r * 8192 + tid * 16;
      int kb2 = ofs >> 12, rem = ofs & 4095;
      sreg[r] = *(const uint4*)((const char*)XeP + ((size_t)kb2 * 32768 + bt0) * 64 + rem);
    }
  }

  for (int it = 0; it < 2; ++it) {
    int bt0 = (blockIdx.x + it * 256) * 64;
    __syncthreads();
    #pragma unroll
    for (int r = 0; r < 4; ++r)
      *(uint4*)((char*)Bt + r * 8192 + tid * 16) = sreg[r];
    __syncthreads();
    if (it == 0) {
      size_t bt0n = ((size_t)blockIdx.x + 256) * 64;
      #pragma unroll
      for (int r = 0; r < 4; ++r) {
        int ofs = r * 8192 + tid * 16;
        int kb2 = ofs >> 12, rem = ofs & 4095;
        sreg[r] = *(const uint4*)((const char*)XeP + ((size_t)kb2 * 32768 + bt0n) * 64 + rem);
      }
    }

    f32x4 acc[4][4];
    #pragma unroll
    for (int rt = 0; rt < 4; ++rt)
      #pragma unroll
      for (int ct = 0; ct < 4; ++ct)
        acc[rt][ct] = (f32x4){0.f, 0.f, 0.f, 0.f};

    #pragma unroll
    for (int kc = 0; kc < 8; ++kc) {
      bf16x8 bfr[4];
      #pragma unroll
      for (int ct = 0; ct < 4; ++ct) {
        int btL = ct * 16 + lr;
        bfr[ct] = *(const bf16x8*)&Bt[kc * 2048 + btL * 32 + ((lg ^ (btL & 3)) * 8)];
      }
      #pragma unroll
      for (int rt = 0; rt < 4; ++rt)
        #pragma unroll
        for (int ct = 0; ct < 4; ++ct)
          acc[rt][ct] = mfma16(gf[rt][kc], bfr[ct], acc[rt][ct]);
    }

    float lse[4][4];
    #pragma unroll
    for (int rt = 0; rt < 4; ++rt) {
      f32x4 cc = *(f32x4*)&ccs[w * 64 + rt * 16 + lg * 4];
      #pragma unroll
      for (int ct = 0; ct < 4; ++ct) {
        f32x4 v = acc[rt][ct] + cc;
        float mx = fmaxf(fmaxf(v[0], v[1]), fmaxf(v[2], v[3]));
        mx = fmaxf(mx, __shfl_xor(mx, 16));
        float sum = expf(v[0] - mx) + expf(v[1] - mx) + expf(v[2] - mx) + expf(v[3] - mx);
        sum += __shfl_xor(sum, 16);
        lse[rt][ct] = mx + logf(sum);
      }
    }
    #pragma unroll
    for (int ct = 0; ct < 4; ++ct) {
      float cm = fmaxf(fmaxf(lse[0][ct], lse[1][ct]), fmaxf(lse[2][ct], lse[3][ct]));
      cm = fmaxf(cm, __shfl_xor(cm, 32));
      if (lg == 0) wavemax[w][ct * 16 + lr] = cm;
    }
    __syncthreads();
    if (w == 0) {
      float cm = wavemax[0][lane];
      #pragma unroll
      for (int ww = 1; ww < 8; ++ww) cm = fmaxf(cm, wavemax[ww][lane]);
      colmax[lane] = cm;
      cmax[(size_t)bt0 + lane] = cm;
    }
    __syncthreads();
    #pragma unroll
    for (int ct = 0; ct < 4; ++ct) {
      float cm = colmax[ct * 16 + lr];
      #pragma unroll
      for (int rt = 0; rt < 4; ++rt) {
        float v = expf(lse[rt][ct] - cm);
        if (!(lg & 1))
          ehat[((size_t)bt0 + ct * 16 + lr) * 64 + (w * 8 + rt * 2 + (lg >> 1))] = v;
      }
    }
  }
}

// ---------------- K4: per-chunk product, single fat wave ---------------------
// r7 diet: per-step instruction cuts (the proven K4 lever — r4's VALU diet
// helped, r1's residency was neutral; wave-steps/SIMD is fixed at 32 so
// per-step issue is all that matters): (1) first MFMA accumulates from a
// loop-invariant zero tuple (kills 32 zero-init movs/step); (2) 2-step
// ping-pong e-unroll (kills 32 ecur=enxt copy movs/step).
#define K4_LOADE(EV, STEP_)                                                    \
  { _Pragma("unroll") for (int cm = 0; cm < 2; ++cm)                           \
      _Pragma("unroll") for (int q = 0; q < 4; ++q)                            \
        EV[cm][q] = *(const f32x4*)&elds[(STEP_) * 64 + cm * 32 + q * 8 + hi * 4]; }

#define K4_STEP(EV)                                                            \
  { __builtin_amdgcn_s_setprio(1);                                             \
    _Pragma("unroll") for (int s = 0; s < 2; ++s) {                            \
      bf16x8 B[4];                                                             \
      _Pragma("unroll") for (int kb = 0; kb < 4; ++kb) {                       \
        int cm = kb >> 1, kbl = kb & 1;                                        \
        int4 wrd;                                                              \
        _Pragma("unroll") for (int p = 0; p < 2; ++p) {                        \
          unsigned avv = P[s][cm][2 * kbl + 1][p];                             \
          unsigned bvv = P[s][cm][2 * kbl][p];                                 \
          asm("v_permlane32_swap_b32 %0, %1" : "+v"(avv), "+v"(bvv));          \
          if (p == 0) { wrd.x = (int)bvv; wrd.z = (int)avv; }                  \
          else        { wrd.y = (int)bvv; wrd.w = (int)avv; }                  \
        }                                                                      \
        B[kb] = *(bf16x8*)&wrd;                                                \
      }                                                                        \
      f32x16 d0 = mfma32(af[0][0], B[0], Z16);                                 \
      f32x16 d1 = mfma32(af[1][0], B[0], Z16);                                 \
      _Pragma("unroll") for (int kb = 1; kb < 4; ++kb) {                       \
        d0 = mfma32(af[0][kb], B[kb], d0);                                     \
        d1 = mfma32(af[1][kb], B[kb], d1);                                     \
      }                                                                        \
      _Pragma("unroll") for (int q = 0; q < 4; ++q)                            \
        _Pragma("unroll") for (int p = 0; p < 2; ++p) {                        \
          P[s][0][q][p] = cvtpk(d0[4 * q + 2 * p] * EV[0][q][2 * p],           \
                                d0[4 * q + 2 * p + 1] * EV[0][q][2 * p + 1]);  \
          P[s][1][q][p] = cvtpk(d1[4 * q + 2 * p] * EV[1][q][2 * p],           \
                                d1[4 * q + 2 * p + 1] * EV[1][q][2 * p + 1]);  \
        }                                                                      \
    }                                                                          \
    __builtin_amdgcn_s_setprio(0); }

#define K4_RESCALE()                                                           \
  { float m = 0.f;                                                             \
    _Pragma("unroll") for (int s = 0; s < 2; ++s)                              \
      _Pragma("unroll") for (int cm = 0; cm < 2; ++cm)                         \
        _Pragma("unroll") for (int q = 0; q < 4; ++q)                          \
          _Pragma("unroll") for (int p = 0; p < 2; ++p) {                      \
            unsigned u = P[s][cm][q][p];                                       \
            m = fmaxf(m, __uint_as_float(u << 16));                            \
            m = fmaxf(m, __uint_as_float(u & 0xffff0000u));                    \
          }                                                                    \
    _Pragma("unroll") for (int off = 1; off < 64; off <<= 1)                   \
      m = fmaxf(m, __shfl_xor(m, off));                                        \
    float inv = 1.0f / m;                                                      \
    _Pragma("unroll") for (int s = 0; s < 2; ++s)                              \
      _Pragma("unroll") for (int cm = 0; cm < 2; ++cm)                         \
        _Pragma("unroll") for (int q = 0; q < 4; ++q)                          \
          _Pragma("unroll") for (int p = 0; p < 2; ++p) {                      \
            unsigned u = P[s][cm][q][p];                                       \
            P[s][cm][q][p] = cvtpk(__uint_as_float(u << 16) * inv,             \
                                   __uint_as_float(u & 0xffff0000u) * inv);    \
          }                                                                    \
    logscale += logf(m); }

__global__ __launch_bounds__(64) void mmm_chunk_kernel(
    const short* __restrict__ WTbf, const float* __restrict__ ehat,
    const float* __restrict__ cmax, float* __restrict__ NT,
    float* __restrict__ aux) {
  __shared__ __align__(16) float elds[1024];  // 16 steps x 64 rows
  int chunk = blockIdx.x, b = blockIdx.y;
  int lane = threadIdx.x;
  int l31 = lane & 31, hi = lane >> 5;

  int t0 = (chunk == 0) ? 1 : chunk * 16;
  int nsteps = (chunk == 0) ? 15 : 16;
  const float* eb = ehat + (size_t)b * 4096 * 64;

  // stage e-slice first (issue-early): rows t0..t0+15 are always in-bounds
  {
    const float* esrc = eb + (size_t)t0 * 64;
    #pragma unroll
    for (int r = 0; r < 4; ++r)
      *(f32x4*)&elds[r * 256 + lane * 4] = *(const f32x4*)&esrc[r * 256 + lane * 4];
  }

  // A = W^T: af[wi][kb], row = wi*32+l31, k = kb*16 + hi*8 + j (shared by strips)
  bf16x8 af[2][4];
  #pragma unroll
  for (int wi = 0; wi < 2; ++wi)
    #pragma unroll
    for (int kb = 0; kb < 4; ++kb)
      af[wi][kb] = *(const bf16x8*)&WTbf[(wi * 32 + l31) * 64 + kb * 16 + hi * 8];

  // packed state: P[s][cm][q][p] = bf16 rows {32cm+8q+4hi+2p, +1} at col s*32+l31
  unsigned P[2][2][4][2];
  #pragma unroll
  for (int s = 0; s < 2; ++s) {
    int col = s * 32 + l31;
    #pragma unroll
    for (int cm = 0; cm < 2; ++cm)
      #pragma unroll
      for (int q = 0; q < 4; ++q)
        #pragma unroll
        for (int p = 0; p < 2; ++p) {
          int row = 32 * cm + 8 * q + 4 * hi + 2 * p;
          unsigned lo = (row == col) ? 0x3F80u : 0u;       // bf16(1.0)
          unsigned h16 = (row + 1 == col) ? 0x3F80u : 0u;
          P[s][cm][q][p] = lo | (h16 << 16);
        }
  }

  f32x16 Z16;   // loop-invariant zero accumulator seed (16 regs, set once)
  #pragma unroll
  for (int r = 0; r < 16; ++r) Z16[r] = 0.f;

  __syncthreads();  // e-slice visible wave-wide

  float logscale = 0.f;
  f32x4 eA[2][4], eB[2][4];
  K4_LOADE(eA, 0)
  K4_LOADE(eB, 1)   // nsteps >= 15, always valid

  int it = 0;
  for (;;) {
    K4_STEP(eA)
    if ((it & 7) == 7) K4_RESCALE()
    ++it;
    if (it == nsteps) break;
    if (it + 1 < nsteps) K4_LOADE(eA, it + 1)
    K4_STEP(eB)
    if ((it & 7) == 7) K4_RESCALE()
    ++it;
    if (it == nsteps) break;
    if (it + 1 < nsteps) K4_LOADE(eB, it + 1)
  }

  // store N_c f32 row-major [row][col]
  float* No = NT + (((size_t)b * 256 + chunk) << 12);
  #pragma unroll
  for (int s = 0; s < 2; ++s)
    #pragma unroll
    for (int cm = 0; cm < 2; ++cm)
      #pragma unroll
      for (int q = 0; q < 4; ++q)
        #pragma unroll
        for (int p = 0; p < 2; ++p) {
          int row = 32 * cm + 8 * q + 4 * hi + 2 * p;
          int col = s * 32 + l31;
          unsigned u = P[s][cm][q][p];
          No[row * 64 + col] = __uint_as_float(u << 16);
          No[(row + 1) * 64 + col] = __uint_as_float(u & 0xffff0000u);
        }

  // aux[b][chunk] = sum cmax + chunk logscale (single scale, whole chunk)
  float cs = (lane < nsteps) ? cmax[(size_t)b * 4096 + t0 + lane] : 0.f;
  #pragma unroll
  for (int off = 1; off < 64; off <<= 1) cs += __shfl_xor(cs, off);
  if (lane == 0) aux[(size_t)b * 256 + chunk] = cs + logscale;
}

// ---------------- K5: merge 16 chunks -> group matrix (16 groups/batch) -----
// r7: rescale every 4th product only (bf16 range analysis: growth <= 64^3,
// shrink ~1e-30 over 4 products — both safely in-range). Removes the wmax
// reduce + mid-barrier + 16 scale-muls on 12/16 iterations. cc=15 still
// rescales, so G2T/auxg semantics unchanged.
__global__ __launch_bounds__(256) void mmm_merge_kernel(
    const float* __restrict__ NT, const float* __restrict__ aux,
    float* __restrict__ G2T, float* __restrict__ auxg) {
  int g = blockIdx.x, b = blockIdx.y;
  int tid = threadIdx.x;
  int w = tid >> 6, lane = tid & 63;
  int wi = w >> 1, wj = w & 1;
  int lr = lane & 15, lg = lane >> 4;

  __shared__ __align__(16) short L[2][4096];
  __shared__ float wmax[4];

  for (int idx = tid; idx < 4096; idx += 256) {
    int j = idx >> 6, k = idx & 63;
    L[0][idx ^ ((j & 7) << 3)] = (j == k) ? (short)0x3F80 : (short)0;
  }
  __syncthreads();

  int cbase = b * 256 + g * 16;

  float logscale = 0.f;
  int cur = 0;
  f32x4 acc[2][2];

  f32x4 apre[2][2][2];
  {
    const float* Mc = NT + ((size_t)cbase << 12);
    #pragma unroll
    for (int rt = 0; rt < 2; ++rt)
      #pragma unroll
      for (int kc = 0; kc < 2; ++kc) {
        const float* src = Mc + (wi * 32 + rt * 16 + lr) * 64 + kc * 32 + lg * 8;
        apre[rt][kc][0] = *(const f32x4*)src;
        apre[rt][kc][1] = *(const f32x4*)(src + 4);
      }
  }

  for (int cc = 0; cc < 16; ++cc) {
    f32x4 acur[2][2][2];
    #pragma unroll
    for (int rt = 0; rt < 2; ++rt)
      #pragma unroll
      for (int kc = 0; kc < 2; ++kc) {
        acur[rt][kc][0] = apre[rt][kc][0];
        acur[rt][kc][1] = apre[rt][kc][1];
      }
    if (cc < 15) {
      const float* Mc = NT + ((size_t)(cbase + cc + 1) << 12);
      #pragma unroll
      for (int rt = 0; rt < 2; ++rt)
        #pragma unroll
        for (int kc = 0; kc < 2; ++kc) {
          const float* src = Mc + (wi * 32 + rt * 16 + lr) * 64 + kc * 32 + lg * 8;
          apre[rt][kc][0] = *(const f32x4*)src;
          apre[rt][kc][1] = *(const f32x4*)(src + 4);
        }
    }

    // single scale per chunk: just accumulate the log
    logscale += aux[cbase + cc];

    bf16x8 afr[2][2];
    #pragma unroll
    for (int rt = 0; rt < 2; ++rt)
      #pragma unroll
      for (int kc = 0; kc < 2; ++kc) {
        unsigned fw[4];
        fw[0] = cvtpk(acur[rt][kc][0][0], acur[rt][kc][0][1]);
        fw[1] = cvtpk(acur[rt][kc][0][2], acur[rt][kc][0][3]);
        fw[2] = cvtpk(acur[rt][kc][1][0], acur[rt][kc][1][1]);
        fw[3] = cvtpk(acur[rt][kc][1][2], acur[rt][kc][1][3]);
        afr[rt][kc] = *(bf16x8*)fw;
      }

    bf16x8 bfr[2][2];
    #pragma unroll
    for (int ct = 0; ct < 2; ++ct) {
      int j = wj * 32 + ct * 16 + lr;
      int sw = (j & 7) << 3;
      #pragma unroll
      for (int kc = 0; kc < 2; ++kc)
        bfr[ct][kc] = *(const bf16x8*)&L[cur][(j * 64 + kc * 32 + lg * 8) ^ sw];
    }

    #pragma unroll
    for (int rt = 0; rt < 2; ++rt)
      #pragma unroll
      for (int ct = 0; ct < 2; ++ct) {
        f32x4 c = {0.f, 0.f, 0.f, 0.f};
        c = mfma16(afr[rt][0], bfr[ct][0], c);
        c = mfma16(afr[rt][1], bfr[ct][1], c);
        acc[rt][ct] = c;
      }

    if ((cc & 3) == 3) {  // rescale every 4th product
      float m = 0.f;
      #pragma unroll
      for (int rt = 0; rt < 2; ++rt)
        #pragma unroll
        for (int ct = 0; ct < 2; ++ct)
          #pragma unroll
          for (int r = 0; r < 4; ++r) m = fmaxf(m, acc[rt][ct][r]);
      #pragma unroll
      for (int off = 1; off < 64; off <<= 1) m = fmaxf(m, __shfl_xor(m, off));
      if (lane == 0) wmax[w] = m;
      __syncthreads();
      m = fmaxf(fmaxf(wmax[0], wmax[1]), fmaxf(wmax[2], wmax[3]));
      float inv = 1.0f / m;
      #pragma unroll
      for (int rt = 0; rt < 2; ++rt)
        #pragma unroll
        for (int ct = 0; ct < 2; ++ct) acc[rt][ct] *= inv;
      logscale += logf(m);
    }

    int nxt = cur ^ 1;
    unsigned* L32 = (unsigned*)&L[nxt][0];
    #pragma unroll
    for (int rt = 0; rt < 2; ++rt)
      #pragma unroll
      for (int ct = 0; ct < 2; ++ct) {
        int row0 = wi * 32 + rt * 16 + lg * 4;   // 4-aligned
        int col = wj * 32 + ct * 16 + lr;
        int sidx = (col * 64 + row0) ^ ((col & 7) << 3);  // XOR hits bits>=3 only
        L32[(sidx >> 1) + 0] = cvtpk(acc[rt][ct][0], acc[rt][ct][1]);
        L32[(sidx >> 1) + 1] = cvtpk(acc[rt][ct][2], acc[rt][ct][3]);
      }
    __syncthreads();
    cur = nxt;
  }

  float* Mo = G2T + (((size_t)b * 16 + g) << 12);
  #pragma unroll
  for (int rt = 0; rt < 2; ++rt)
    #pragma unroll
    for (int ct = 0; ct < 2; ++ct)
      #pragma unroll
      for (int r = 0; r < 4; ++r) {
        int row = wi * 32 + rt * 16 + lg * 4 + r;
        int col = wj * 32 + ct * 16 + lr;
        Mo[row * 64 + col] = acc[rt][ct][r];
      }

  if (w == 0 && lane == 0) auxg[b * 16 + g] = logscale;
}

// ---------------- K6: final combine (16 group matrices per batch) -----------
__global__ __launch_bounds__(64) void mmm_combine_kernel(
    const float* __restrict__ pi_logits, const float* __restrict__ ehat,
    const float* __restrict__ cmax, const float* __restrict__ G2T,
    const float* __restrict__ auxg, float* __restrict__ out) {
  int b = blockIdx.x, lane = threadIdx.x;
  __shared__ __align__(16) float alds[64];

  float pv = pi_logits[lane];
  float mx = pv;
  #pragma unroll
  for (int off = 1; off < 64; off <<= 1) mx = fmaxf(mx, __shfl_xor(mx, off));
  float pe = expf(pv - mx);
  float ps = pe;
  #pragma unroll
  for (int off = 1; off < 64; off <<= 1) ps += __shfl_xor(ps, off);

  float a = (pe / ps) * ehat[(size_t)b * 4096 * 64 + lane];
  double logtot = (double)cmax[(size_t)b * 4096];
  alds[lane] = a;
  __builtin_amdgcn_wave_barrier();

  const float* Mb = G2T + (((size_t)b * 16) << 12) + lane * 64;
  f32x4 mc[16], mn[16];
  #pragma unroll
  for (int i = 0; i < 16; ++i) mc[i] = *(const f32x4*)&Mb[i * 4];

  for (int g = 0; g < 16; ++g) {
    if (g < 15) {
      const float* Mn = Mb + ((size_t)(g + 1) << 12);
      #pragma unroll
      for (int i = 0; i < 16; ++i) mn[i] = *(const f32x4*)&Mn[i * 4];
    }
    f32x4 a4 = {0.f, 0.f, 0.f, 0.f};
    #pragma unroll
    for (int i = 0; i < 16; ++i) {
      f32x4 av = *(const f32x4*)&alds[i * 4];
      a4 += mc[i] * av;
    }
    float acc = (a4[0] + a4[1]) + (a4[2] + a4[3]);
    float s = acc;
    #pragma unroll
    for (int off = 1; off < 64; off <<= 1) s += __shfl_xor(s, off);
    logtot += (double)(auxg[b * 16 + g] + logf(s));
    float an = acc / s;
    __builtin_amdgcn_wave_barrier();
    alds[lane] = an;
    __builtin_amdgcn_wave_barrier();
    #pragma unroll
    for (int i = 0; i < 16; ++i) mc[i] = mn[i];
  }
  if (lane == 0) out[b] = (float)logtot;
}

extern "C" void kernel_launch(void* const* d_in, const int* in_sizes, int n_in,
                              void* d_out, int out_size, void* d_ws, size_t ws_size,
                              hipStream_t stream) {
  const float* X      = (const float*)d_in[0];
  const float* pi_l   = (const float*)d_in[1];
  const float* tr_l   = (const float*)d_in[2];
  const float* wl     = (const float*)d_in[3];
  const float* means  = (const float*)d_in[4];
  const float* lvs    = (const float*)d_in[5];
  float* out = (float*)d_out;

  float* ws = (float*)d_ws;
  short* Gt      = (short*)ws;                 // 131072 shorts = 65536 f32
  float* const_c = ws + 65536;                 // 512
  short* WTbf    = (short*)(ws + 66048);       // 4096 shorts = 2048 f32
  float* cmaxp   = ws + 68608;                 // 32768
  float* ehat    = ws + 101376;                // 2097152
  short* XeP     = (short*)(ws + 2198528);     // 16 MB
  float* NT      = ws + 2198528;               // aliases XeP (dead after emis); 8388608 f32
  float* aux     = ws + 10587136;              // 2048 (256 chunks x 8 b)
  float* G2T     = ws + 10591232;              // 524288 (8 b x 16 g x 4096)
  float* auxg    = ws + 11115520;              // 128

  mmm_prep_fused<<<832, 256, 0, stream>>>(tr_l, means, lvs, wl, X,
                                          WTbf, Gt, const_c, XeP);
  mmm_emis_kernel<<<256, 512, 0, stream>>>(Gt, XeP, const_c, ehat, cmaxp);
  mmm_chunk_kernel<<<dim3(256, 8), 64, 0, stream>>>(WTbf, ehat, cmaxp, NT, aux);
  mmm_merge_kernel<<<dim3(16, 8), 256, 0, stream>>>(NT, aux, G2T, auxg);
  mmm_combine_kernel<<<8, 64, 0, stream>>>(pi_l, ehat, cmaxp, G2T, auxg, out);
}